// Round 2
// baseline (656.221 us; speedup 1.0000x reference)
//
#include <hip/hip_runtime.h>

typedef __attribute__((ext_vector_type(8))) short short8;
typedef __attribute__((ext_vector_type(8))) __bf16 bf16x8;
typedef __attribute__((ext_vector_type(4))) float f32x4;

__device__ __forceinline__ short f2bf(float f) {
    union { float f; unsigned u; } x; x.f = f;
    unsigned r = (x.u + 0x7FFFu + ((x.u >> 16) & 1u)) >> 16;
    return (short)r;
}

__device__ __forceinline__ f32x4 mfma16(bf16x8 a, bf16x8 b, f32x4 c) {
    return __builtin_amdgcn_mfma_f32_16x16x32_bf16(a, b, c, 0, 0, 0);
}

// ---------------------------------------------------------------------------
// Weight repack: fp32 row-major (Kreal x 1024) -> bf16 MFMA-B fragment order.
// Chunk c = nf*nK + t holds the (k=32 x n=16) tile: lane l owns 8 bf16 at
// k = t*32 + (l>>4)*8 + j, n = nf*16 + (l&15). 16B/lane, 1KB/chunk.
// perm=1: source row is pi^-1(k) (k-space permutation for the fused GEMM2,
// matching the epilogue's packed-Y layout; GEMM invariant under shared K-perm).
// ---------------------------------------------------------------------------
struct WConvP {
    const float* src[8];
    short*       dst[8];
    int          Kreal[8];
    int          nK[8];
    int          perm[8];
};

__global__ __launch_bounds__(256) void k_wconv(WConvP P) {
    int y = blockIdx.y;
    int nK = P.nK[y];
    int nchunks = nK << 6;
    int c = blockIdx.x * 4 + (threadIdx.x >> 6);
    if (c >= nchunks) return;
    int l = threadIdx.x & 63;
    int t = c % nK, nf = c / nK;
    int k0 = (t << 5) + ((l >> 4) << 3);
    int n  = (nf << 4) + (l & 15);
    const float* src = P.src[y];
    int Kreal = P.Kreal[y];
    int pm = P.perm[y];
    short8 v;
#pragma unroll
    for (int j = 0; j < 8; ++j) {
        int kk = k0 + j;
        int sr = pm ? ((kk & ~127) | ((kk & 7) << 4) | ((kk >> 3) & 15)) : kk;
        float f = (kk < Kreal) ? src[(size_t)sr * 1024 + n] : 0.f;
        v[j] = f2bf(f);
    }
    ((short8*)P.dst[y])[(size_t)c * 64 + l] = v;
}

// ---------------------------------------------------------------------------
// Build bf16 [row, 2080] zero-padded concat inputs.
// ---------------------------------------------------------------------------
__global__ __launch_bounds__(256) void k_build(const float* box_feats, const float* box_coords,
                                               const float* pooled, const float* pool_coords,
                                               short* bfc, short* pc) {
    int id = blockIdx.x * 256 + threadIdx.x;
    if (blockIdx.y == 0) {
        if (id >= 512 * 2080) return;
        int row = id / 2080, kp = id - row * 2080;
        int b = row >> 7, i = row & 127;
        float v = 0.f;
        if (kp < 2048)      v = box_feats[((size_t)(b * 128 + i)) * 2048 + kp];
        else if (kp < 2052) v = box_coords[(b * 128 + i) * 4 + (kp - 2048)];
        bfc[id] = f2bf(v);
    } else {
        if (id >= 64 * 2080) return;
        int row = id / 2080, kp = id - row * 2080;
        int b = row >> 4, j = row & 15;
        float v = 0.f;
        if (kp < 2048)      v = pooled[((size_t)(b * 16 + j)) * 2048 + kp];
        else if (kp < 2052) v = pool_coords[j * 4 + (kp - 2048)];
        pc[id] = f2bf(v);
    }
}

// ---------------------------------------------------------------------------
// hq1 = q @ W1q + g1_b1 ; hq2 = q @ W2q + g2_b1 (fp32, tiny; folded into A1/A2)
// ---------------------------------------------------------------------------
__global__ __launch_bounds__(256) void k_hq(const float* q_feats,
                                            const float* g1_w1, const float* g1_b1,
                                            const float* g2_w1, const float* g2_b1,
                                            float* hq1, float* hq2) {
    int id = blockIdx.x * 256 + threadIdx.x;
    int s = id >> 12, b = (id >> 10) & 3, n = id & 1023;
    const float* W = (s ? g2_w1 : g1_w1) + (size_t)4104 * 1024 + n;
    const float* q = q_feats + b * 1024;
    float acc = s ? g2_b1[n] : g1_b1[n];
    for (int k = 0; k < 1024; k += 8) {
#pragma unroll
        for (int u = 0; u < 8; ++u) acc += q[k + u] * W[(size_t)(k + u) * 1024];
    }
    (s ? hq2 : hq1)[b * 1024 + n] = acc;
}

// ---------------------------------------------------------------------------
// Stage-1 GEMMs: Out(M,1024) = X(M,2080 bf16) @ Wfrag (+ optional hq[b]).
// ---------------------------------------------------------------------------
struct Stage1P {
    const short*  X[4];
    const short8* Wf[4];
    float*        Out[4];
    const float*  addv[4];
    int           M[4];
};

__global__ __launch_bounds__(512) void k_stage1(Stage1P P) {
    int z = blockIdx.z;
    int M = P.M[z];
    int m0 = blockIdx.x << 5;
    if (m0 >= M) return;
    const short*  Xg = P.X[z];
    const short8* Wf = P.Wf[z];
    float* Out = P.Out[z];
    const float* av = P.addv[z];
    int tid = threadIdx.x, w = tid >> 6, l = tid & 63, lr = l & 15, lh = l >> 4;
    const short8* Wl = Wf + (size_t)(w << 3) * 65 * 64 + l;
    f32x4 z4 = {0.f, 0.f, 0.f, 0.f};
    f32x4 acc[2][8];
#pragma unroll
    for (int mf = 0; mf < 2; ++mf)
#pragma unroll
        for (int f = 0; f < 8; ++f) acc[mf][f] = z4;

    for (int t = 0; t < 65; ++t) {
        int k0 = (t << 5) + (lh << 3);
        bf16x8 a0 = __builtin_bit_cast(bf16x8, *(const short8*)(Xg + (size_t)(m0 + lr) * 2080 + k0));
        bf16x8 a1 = __builtin_bit_cast(bf16x8, *(const short8*)(Xg + (size_t)(m0 + 16 + lr) * 2080 + k0));
#pragma unroll
        for (int f = 0; f < 8; ++f) {
            bf16x8 bb = __builtin_bit_cast(bf16x8, Wl[(size_t)f * 65 * 64 + (size_t)t * 64]);
            acc[0][f] = mfma16(a0, bb, acc[0][f]);
            acc[1][f] = mfma16(a1, bb, acc[1][f]);
        }
    }
#pragma unroll
    for (int mf = 0; mf < 2; ++mf)
#pragma unroll
        for (int f = 0; f < 8; ++f)
#pragma unroll
            for (int r = 0; r < 4; ++r) {
                int row = m0 + (mf << 4) + (lh << 2) + r;
                int col = (w << 7) + (f << 4) + lr;
                float extra = av ? av[((row >> 7) << 10) + col] : 0.f;
                Out[(size_t)row * 1024 + col] = acc[mf][f][r] + extra;
            }
}

// ---------------------------------------------------------------------------
// Fused relation-net tile kernel, M=64 (raises AI vs L2 to ~67 FLOP/B).
// LDS 128KB: X (64 rows x 1024, bf16, A-frag chunks), reused in-place for Y.
// phase1: X=relu(A[i]+B[j]) -> GEMM1(W2,relu) -> Y (k-permuted pack) ->
// GEMM2(W3 with pi^-1-permuted rows) -> masked row-sum -> atomicAdd gsum.
// XOR swizzle slot^=(slot>>6)&3 on every LDS access: packed epilogue writes
// and all frag reads are bank-conflict-free.
// ---------------------------------------------------------------------------
struct FuseP {
    const float*  Arow;   // A (+hq folded), 128 rows/sample
    const float*  Brow;
    const short8* W2;
    const short8* W3;
    const float*  b2;
    const float*  b3;
    float*        gsum;
    const int*    index;
    int           mode;   // 0: pairs=n*n (B=128 rows), 1: pairs=n*16 (B=16 rows)
};

__global__ __launch_bounds__(512, 2) void k_fused(FuseP P) {
    __shared__ short8 XL[8192];                       // 128 KiB
    int b  = blockIdx.y;
    int nv = P.index[b];
    int npairs = P.mode ? (nv << 4) : (nv * nv);
    int p0 = blockIdx.x << 6;
    if (p0 >= npairs) return;
    int tid = threadIdx.x, w = tid >> 6, l = tid & 63, lr = l & 15, lh = l >> 4;
    int bstr = P.mode ? 16 : 128;
    const float* Arow = P.Arow + (size_t)b * 128 * 1024;
    const float* Brow = P.Brow + (size_t)b * bstr * 1024;

    // ---- phase 1: X tile (one pair-row per (wave-half, lr); 16 k-chunks)
    {
        int mfp = w >> 1;
        int p = p0 + (mfp << 4) + lr;
        int i = 0, j = 0;
        if (p < npairs) {
            if (P.mode) { i = p >> 4; j = p & 15; }
            else        { i = (int)((unsigned)p / (unsigned)nv); j = p - i * nv; }
        }
        const float* Ap = Arow + (size_t)i * 1024;
        const float* Bp = Brow + (size_t)j * 1024;
        int tbase = (w & 1) << 4;
#pragma unroll
        for (int cc = 0; cc < 16; ++cc) {
            int t = tbase + cc;
            int k0 = (t << 5) + (lh << 3);
            f32x4 a0 = *(const f32x4*)(Ap + k0), a1 = *(const f32x4*)(Ap + k0 + 4);
            f32x4 b0 = *(const f32x4*)(Bp + k0), b1 = *(const f32x4*)(Bp + k0 + 4);
            short8 v;
#pragma unroll
            for (int e = 0; e < 4; ++e) {
                v[e]     = f2bf(fmaxf(a0[e] + b0[e], 0.f));
                v[4 + e] = f2bf(fmaxf(a1[e] + b1[e], 0.f));
            }
            int slot = (((mfp << 5) + t) << 6) + l;
            XL[slot ^ ((slot >> 6) & 3)] = v;
        }
    }
    float b2l[8], b3l[8];
#pragma unroll
    for (int f = 0; f < 8; ++f) {
        int n = (w << 7) + (f << 4) + lr;
        b2l[f] = P.b2[n];
        b3l[f] = P.b3[n];
    }
    __syncthreads();

    // ---- GEMM1: Y = X @ W2
    const short8* W2l = P.W2 + (size_t)(w << 3) * 2048 + l;
    f32x4 z4 = {0.f, 0.f, 0.f, 0.f};
    f32x4 acc[4][8];
#pragma unroll
    for (int mf = 0; mf < 4; ++mf)
#pragma unroll
        for (int f = 0; f < 8; ++f) acc[mf][f] = z4;
    for (int t = 0; t < 32; ++t) {
        bf16x8 a[4];
#pragma unroll
        for (int mf = 0; mf < 4; ++mf) {
            int slot = (((mf << 5) + t) << 6) + l;
            a[mf] = __builtin_bit_cast(bf16x8, XL[slot ^ ((slot >> 6) & 3)]);
        }
#pragma unroll
        for (int f = 0; f < 8; ++f) {
            bf16x8 bb = __builtin_bit_cast(bf16x8, W2l[(f << 11) + (t << 6)]);
#pragma unroll
            for (int mf = 0; mf < 4; ++mf)
                acc[mf][f] = mfma16(a[mf], bb, acc[mf][f]);
        }
    }
    __syncthreads();                                   // all X reads done

    // ---- epilogue 1: Y[m][k'=w*128+lr*8+f] = relu(acc+b2), one b128/(mf,r)
#pragma unroll
    for (int mf = 0; mf < 4; ++mf)
#pragma unroll
        for (int r = 0; r < 4; ++r) {
            short8 v;
#pragma unroll
            for (int f = 0; f < 8; ++f)
                v[f] = f2bf(fmaxf(acc[mf][f][r] + b2l[f], 0.f));
            int slot = (((mf << 5) + (w << 2) + (lr >> 2)) << 6)
                     + ((lr & 3) << 4) + (lh << 2) + r;
            XL[slot ^ ((slot >> 6) & 3)] = v;
        }
    __syncthreads();

    // ---- GEMM2: Z = Y @ W3 (k'-space; W3 rows pre-permuted by pi^-1)
    const short8* W3l = P.W3 + (size_t)(w << 3) * 2048 + l;
#pragma unroll
    for (int mf = 0; mf < 4; ++mf)
#pragma unroll
        for (int f = 0; f < 8; ++f) acc[mf][f] = z4;
    for (int t = 0; t < 32; ++t) {
        bf16x8 a[4];
#pragma unroll
        for (int mf = 0; mf < 4; ++mf) {
            int slot = (((mf << 5) + t) << 6) + l;
            a[mf] = __builtin_bit_cast(bf16x8, XL[slot ^ ((slot >> 6) & 3)]);
        }
#pragma unroll
        for (int f = 0; f < 8; ++f) {
            bf16x8 bb = __builtin_bit_cast(bf16x8, W3l[(f << 11) + (t << 6)]);
#pragma unroll
            for (int mf = 0; mf < 4; ++mf)
                acc[mf][f] = mfma16(a[mf], bb, acc[mf][f]);
        }
    }

    // ---- masked row-sum of relu(acc+b3) -> one atomic per (col)
#pragma unroll
    for (int f = 0; f < 8; ++f) {
        float s = 0.f;
#pragma unroll
        for (int mf = 0; mf < 4; ++mf)
#pragma unroll
            for (int r = 0; r < 4; ++r) {
                int m = (mf << 4) + (lh << 2) + r;
                if (p0 + m < npairs) s += fmaxf(acc[mf][f][r] + b3l[f], 0.f);
            }
        s += __shfl_xor(s, 16);
        s += __shfl_xor(s, 32);
        if (l < 16) atomicAdd(&P.gsum[(size_t)b * 1024 + (w << 7) + (f << 4) + l], s);
    }
}

// ---------------------------------------------------------------------------
// Tail (fp32, tiny)
// ---------------------------------------------------------------------------
__global__ __launch_bounds__(256) void k_t1(const float* g1s, const float* g2s,
                                            const float* f1_w, const float* f1_b,
                                            const float* f2_w, const float* f2_b,
                                            float* rn) {
    __shared__ float red[256];
    int bi = blockIdx.x;
    int s = bi >> 6, b = (bi >> 4) & 3, nb = bi & 15;
    int t = threadIdx.x, nl = t & 63, sl = t >> 6;
    int n = (nb << 6) + nl;
    const float* vin = (s ? g2s : g1s) + b * 1024;
    const float* W = s ? f2_w : f1_w;
    float p = 0.f;
    int k0 = sl << 8;
    for (int k = 0; k < 256; ++k) p += vin[k0 + k] * W[(size_t)(k0 + k) * 1024 + n];
    red[t] = p;
    __syncthreads();
    if (t < 64) {
        float tot = red[t] + red[t + 64] + red[t + 128] + red[t + 192];
        const float* bias = s ? f2_b : f1_b;
        int nn = (nb << 6) + t;
        rn[(size_t)b * 2048 + (s << 10) + nn] = fmaxf(tot + bias[nn], 0.f);
    }
}

__global__ __launch_bounds__(256) void k_t2(const float* rn, const float* fg_w1,
                                            const float* fg_b1, float* u) {
    __shared__ float red[256];
    int bi = blockIdx.x;
    int b = bi >> 4, nb = bi & 15;
    int t = threadIdx.x, nl = t & 63, sl = t >> 6;
    int n = (nb << 6) + nl;
    float p = 0.f;
    int k0 = sl << 9;
    for (int k = 0; k < 512; ++k) p += rn[(size_t)b * 2048 + k0 + k] * fg_w1[(size_t)(k0 + k) * 1024 + n];
    red[t] = p;
    __syncthreads();
    if (t < 64) {
        float tot = red[t] + red[t + 64] + red[t + 128] + red[t + 192];
        int nn = (nb << 6) + t;
        u[(size_t)b * 1024 + nn] = fmaxf(tot + fg_b1[nn], 0.f);
    }
}

__global__ __launch_bounds__(256) void k_t3(const float* u, const float* fg_w2,
                                            const float* fg_b2, float* out) {
    __shared__ float red[256];
    int b = blockIdx.x;
    int t = threadIdx.x, c = t & 15, sl = t >> 4;
    float p = 0.f;
    int k0 = sl << 6;
    for (int k = 0; k < 64; ++k) p += u[(size_t)b * 1024 + k0 + k] * fg_w2[(size_t)(k0 + k) * 16 + c];
    red[t] = p;
    __syncthreads();
    if (t < 16) {
        float tot = 0.f;
#pragma unroll
        for (int s2 = 0; s2 < 16; ++s2) tot += red[t + (s2 << 4)];
        out[b * 16 + t] = tot + fg_b2[t];
    }
}

// ---------------------------------------------------------------------------
extern "C" void kernel_launch(void* const* d_in, const int* in_sizes, int n_in,
                              void* d_out, int out_size, void* d_ws, size_t ws_size,
                              hipStream_t stream) {
    (void)in_sizes; (void)n_in; (void)out_size; (void)ws_size;
    const float* pooled      = (const float*)d_in[1];
    const float* box_feats   = (const float*)d_in[2];
    const float* q_feats     = (const float*)d_in[3];
    const float* box_coords  = (const float*)d_in[4];
    const int*   index       = (const int*)d_in[5];
    const float* g1_w1 = (const float*)d_in[6];
    const float* g1_b1 = (const float*)d_in[7];
    const float* g1_w2 = (const float*)d_in[8];
    const float* g1_b2 = (const float*)d_in[9];
    const float* g1_w3 = (const float*)d_in[10];
    const float* g1_b3 = (const float*)d_in[11];
    const float* f1_w  = (const float*)d_in[12];
    const float* f1_b  = (const float*)d_in[13];
    const float* g2_w1 = (const float*)d_in[14];
    const float* g2_b1 = (const float*)d_in[15];
    const float* g2_w2 = (const float*)d_in[16];
    const float* g2_b2 = (const float*)d_in[17];
    const float* g2_w3 = (const float*)d_in[18];
    const float* g2_b3 = (const float*)d_in[19];
    const float* f2_w  = (const float*)d_in[20];
    const float* f2_b  = (const float*)d_in[21];
    const float* fg_w1 = (const float*)d_in[22];
    const float* fg_b1 = (const float*)d_in[23];
    const float* fg_w2 = (const float*)d_in[24];
    const float* fg_b2 = (const float*)d_in[25];
    const float* pool_coords = (const float*)d_in[26];
    float* out = (float*)d_out;

    char* base = (char*)d_ws;
    size_t off = 0;
    auto alloc = [&](size_t bytes) -> void* {
        void* p = base + off;
        off = (off + bytes + 255) & ~(size_t)255;
        return p;
    };
    const size_t szWfBig = (size_t)2080 * 1024 * 2;
    const size_t szWfSm  = (size_t)1024 * 1024 * 2;
    short* WfA   = (short*)alloc(szWfBig);
    short* WfB   = (short*)alloc(szWfBig);
    short* Wf2A  = (short*)alloc(szWfBig);
    short* Wf2B  = (short*)alloc(szWfBig);
    short* Wg1w2 = (short*)alloc(szWfSm);
    short* Wg1w3 = (short*)alloc(szWfSm);
    short* Wg2w2 = (short*)alloc(szWfSm);
    short* Wg2w3 = (short*)alloc(szWfSm);
    short* bfc   = (short*)alloc((size_t)512 * 2080 * 2);
    short* pc    = (short*)alloc((size_t)64 * 2080 * 2);
    float* A1    = (float*)alloc((size_t)512 * 1024 * 4);
    float* B1    = (float*)alloc((size_t)512 * 1024 * 4);
    float* A2    = (float*)alloc((size_t)512 * 1024 * 4);
    float* P2    = (float*)alloc((size_t)64 * 1024 * 4);
    float* hq1   = (float*)alloc((size_t)4096 * 4);
    float* hq2   = (float*)alloc((size_t)4096 * 4);
    float* sums  = (float*)alloc((size_t)2 * 4096 * 4);
    float* g1s   = sums;
    float* g2s   = sums + 4096;
    float* rn    = (float*)alloc((size_t)4 * 2048 * 4);
    float* u     = (float*)alloc((size_t)4 * 1024 * 4);

    // 1. repack weights (W3s get the pi^-1 k-permutation)
    WConvP wp;
    wp.src[0] = g1_w1;                      wp.dst[0] = WfA;   wp.Kreal[0] = 2052; wp.nK[0] = 65; wp.perm[0] = 0;
    wp.src[1] = g1_w1 + (size_t)2052*1024;  wp.dst[1] = WfB;   wp.Kreal[1] = 2052; wp.nK[1] = 65; wp.perm[1] = 0;
    wp.src[2] = g2_w1;                      wp.dst[2] = Wf2A;  wp.Kreal[2] = 2052; wp.nK[2] = 65; wp.perm[2] = 0;
    wp.src[3] = g2_w1 + (size_t)2052*1024;  wp.dst[3] = Wf2B;  wp.Kreal[3] = 2052; wp.nK[3] = 65; wp.perm[3] = 0;
    wp.src[4] = g1_w2;                      wp.dst[4] = Wg1w2; wp.Kreal[4] = 1024; wp.nK[4] = 32; wp.perm[4] = 0;
    wp.src[5] = g1_w3;                      wp.dst[5] = Wg1w3; wp.Kreal[5] = 1024; wp.nK[5] = 32; wp.perm[5] = 1;
    wp.src[6] = g2_w2;                      wp.dst[6] = Wg2w2; wp.Kreal[6] = 1024; wp.nK[6] = 32; wp.perm[6] = 0;
    wp.src[7] = g2_w3;                      wp.dst[7] = Wg2w3; wp.Kreal[7] = 1024; wp.nK[7] = 32; wp.perm[7] = 1;
    k_wconv<<<dim3(1040, 8), 256, 0, stream>>>(wp);

    // 2. padded bf16 activations
    k_build<<<dim3(4160, 2), 256, 0, stream>>>(box_feats, box_coords, pooled, pool_coords, bfc, pc);

    // 3. hq vectors (with first-layer biases)
    k_hq<<<32, 256, 0, stream>>>(q_feats, g1_w1, g1_b1, g2_w1, g2_b1, hq1, hq2);

    // 4. stage-1 GEMMs (hq folded into A1/A2)
    Stage1P sp;
    sp.X[0] = bfc; sp.Wf[0] = (const short8*)WfA;  sp.Out[0] = A1; sp.M[0] = 512; sp.addv[0] = hq1;
    sp.X[1] = bfc; sp.Wf[1] = (const short8*)WfB;  sp.Out[1] = B1; sp.M[1] = 512; sp.addv[1] = nullptr;
    sp.X[2] = bfc; sp.Wf[2] = (const short8*)Wf2A; sp.Out[2] = A2; sp.M[2] = 512; sp.addv[2] = hq2;
    sp.X[3] = pc;  sp.Wf[3] = (const short8*)Wf2B; sp.Out[3] = P2; sp.M[3] = 64;  sp.addv[3] = nullptr;
    k_stage1<<<dim3(16, 1, 4), 512, 0, stream>>>(sp);

    // 5. zero accumulators
    hipMemsetAsync(sums, 0, 2 * 4096 * 4, stream);

    // 6. fused g1 path (pairs = n*n), M=64
    FuseP f1p;
    f1p.Arow = A1; f1p.Brow = B1;
    f1p.W2 = (const short8*)Wg1w2; f1p.W3 = (const short8*)Wg1w3;
    f1p.b2 = g1_b2; f1p.b3 = g1_b3; f1p.gsum = g1s; f1p.index = index; f1p.mode = 0;
    k_fused<<<dim3(256, 4), 512, 0, stream>>>(f1p);

    // 7. fused g2 path (pairs = n*16), M=64
    FuseP f2p;
    f2p.Arow = A2; f2p.Brow = P2;
    f2p.W2 = (const short8*)Wg2w2; f2p.W3 = (const short8*)Wg2w3;
    f2p.b2 = g2_b2; f2p.b3 = g2_b3; f2p.gsum = g2s; f2p.index = index; f2p.mode = 1;
    k_fused<<<dim3(32, 4), 512, 0, stream>>>(f2p);

    // 8-10. tail
    k_t1<<<128, 256, 0, stream>>>(g1s, g2s, f1_w, f1_b, f2_w, f2_b, rn);
    k_t2<<<64, 256, 0, stream>>>(rn, fg_w1, fg_b1, u);
    k_t3<<<4, 256, 0, stream>>>(u, fg_w2, fg_b2, out);
}

// Round 7
// 476.628 us; speedup vs baseline: 1.3768x; 1.3768x over previous
//
#include <hip/hip_runtime.h>

typedef __attribute__((ext_vector_type(8))) short short8;
typedef __attribute__((ext_vector_type(8))) __bf16 bf16x8;
typedef __attribute__((ext_vector_type(4))) float f32x4;

__device__ __forceinline__ short f2bf(float f) {
    union { float f; unsigned u; } x; x.f = f;
    unsigned r = (x.u + 0x7FFFu + ((x.u >> 16) & 1u)) >> 16;
    return (short)r;
}

__device__ __forceinline__ f32x4 mfma16(bf16x8 a, bf16x8 b, f32x4 c) {
    return __builtin_amdgcn_mfma_f32_16x16x32_bf16(a, b, c, 0, 0, 0);
}

// LDS 16B-slot swizzle: injects slot bits 4-6 into bank bits.
__device__ __forceinline__ int swz(int slot) { return slot ^ ((slot >> 4) & 7); }

// ---------------------------------------------------------------------------
// Weight repack: fp32 row-major -> bf16 MFMA-B fragment order.
// Chunk c = nf*nK + t holds (k=32 x n=16): lane l owns 8 bf16 at
// k = t*32 + (l>>4)*8 + j, n = nf*16 + (l&15).
// Big (nK=98) variants append rows: [src0(2052) | 0 | srcq(1024) | bias | 0].
// perm=1 (nK=32): source row pr = (kk&~63)|((kk&3)<<4)|((kk>>2)&15)  (pi^-1
// of the fused epilogue's Y k'-pack; verified algebraically r3 + r4).
// ---------------------------------------------------------------------------
struct WConvP {
    const float* src0[8];
    const float* srcq[8];
    const float* bias[8];
    short*       dst[8];
    int          n0[8];
    int          nK[8];
    int          perm[8];
};

__global__ __launch_bounds__(256) void k_wconv(WConvP P) {
    int y = blockIdx.y;
    int nK = P.nK[y];
    int nchunks = nK << 6;
    int c = blockIdx.x * 4 + (threadIdx.x >> 6);
    if (c >= nchunks) return;
    int l = threadIdx.x & 63;
    int t = c % nK, nf = c / nK;
    int k0 = (t << 5) + ((l >> 4) << 3);
    int n  = (nf << 4) + (l & 15);
    const float* src0 = P.src0[y];
    const float* srcq = P.srcq[y];
    const float* bias = P.bias[y];
    int n0 = P.n0[y], pm = P.perm[y];
    short8 v;
#pragma unroll
    for (int j = 0; j < 8; ++j) {
        int kk = k0 + j;
        float f = 0.f;
        if (pm) {
            int pr = (kk & ~63) | ((kk & 3) << 4) | ((kk >> 2) & 15);
            f = src0[(size_t)pr * 1024 + n];
        } else if (kk < n0) {
            f = src0[(size_t)kk * 1024 + n];
        } else if (srcq && kk >= 2080 && kk < 3104) {
            f = srcq[(size_t)(kk - 2080) * 1024 + n];
        } else if (bias && kk == 3104) {
            f = bias[n];
        }
        v[j] = f2bf(f);
    }
    ((short8*)P.dst[y])[(size_t)c * 64 + l] = v;
}

// ---------------------------------------------------------------------------
// Build bf16 padded X rows.
// bfcq row (b,i), K=3136: [box_feats|box_coords|0x28|q[b]|1.0|0x31]
// pc   row (b,j), K=2080: [pooled|pool_coords|0x28]
// ---------------------------------------------------------------------------
__global__ __launch_bounds__(256) void k_build(const float* box_feats, const float* box_coords,
                                               const float* pooled, const float* pool_coords,
                                               const float* q_feats, short* bfcq, short* pc) {
    int id = blockIdx.x * 256 + threadIdx.x;
    if (blockIdx.y == 0) {
        if (id >= 512 * 3136) return;
        int row = id / 3136, kp = id - row * 3136;
        int b = row >> 7, i = row & 127;
        float v = 0.f;
        if (kp < 2048)       v = box_feats[((size_t)(b * 128 + i)) * 2048 + kp];
        else if (kp < 2052)  v = box_coords[(b * 128 + i) * 4 + (kp - 2048)];
        else if (kp >= 2080 && kp < 3104) v = q_feats[b * 1024 + (kp - 2080)];
        else if (kp == 3104) v = 1.0f;
        bfcq[id] = f2bf(v);
    } else {
        if (id >= 64 * 2080) return;
        int row = id / 2080, kp = id - row * 2080;
        int b = row >> 4, j = row & 15;
        float v = 0.f;
        if (kp < 2048)      v = pooled[((size_t)(b * 16 + j)) * 2048 + kp];
        else if (kp < 2052) v = pool_coords[j * 4 + (kp - 2048)];
        pc[id] = f2bf(v);
    }
}

// ---------------------------------------------------------------------------
// Stage-1 GEMMs, one kernel, 200 blocks x 256 thr (4 waves).
// Block: 32 rows x 256 cols. z0:A1(K98) z1:B1(K65) z2:A2(K98) z3:P2(K65).
// hq + first-layer bias folded into A-paths via the appended X columns.
// ---------------------------------------------------------------------------
struct S1P {
    const short*  X[4];
    const short8* Wf[4];
    float*        Out[4];
    int           xstr[4];
    int           nK[4];
};

__global__ __launch_bounds__(256) void k_stage1(S1P P) {
    int bid = blockIdx.x;
    int z, idx;
    if (bid < 64)       { z = 0; idx = bid; }
    else if (bid < 128) { z = 1; idx = bid - 64; }
    else if (bid < 192) { z = 2; idx = bid - 128; }
    else                { z = 3; idx = bid - 192; }
    int mt = idx >> 2, panel = idx & 3;
    int m0 = mt << 5;
    const short*  Xg = P.X[z];
    const short8* Wf = P.Wf[z];
    float* Out = P.Out[z];
    int xstr = P.xstr[z], nK = P.nK[z];

    int tid = threadIdx.x, w = tid >> 6, l = tid & 63, lr = l & 15, lh = l >> 4;
    int nfb = (panel << 4) + (w << 2);
    const short8* Wl = Wf + (size_t)nfb * nK * 64 + l;
    f32x4 z4 = {0.f, 0.f, 0.f, 0.f};
    f32x4 acc[2][4];
#pragma unroll
    for (int mf = 0; mf < 2; ++mf)
#pragma unroll
        for (int f = 0; f < 4; ++f) acc[mf][f] = z4;

    for (int t = 0; t < nK; ++t) {
        int k0 = (t << 5) + (lh << 3);
        const short* xb = Xg + (size_t)(m0 + lr) * xstr + k0;
        bf16x8 a0 = __builtin_bit_cast(bf16x8, *(const short8*)xb);
        bf16x8 a1 = __builtin_bit_cast(bf16x8, *(const short8*)(xb + (size_t)16 * xstr));
#pragma unroll
        for (int f = 0; f < 4; ++f) {
            bf16x8 bb = __builtin_bit_cast(bf16x8, Wl[((size_t)f * nK + t) << 6]);
            acc[0][f] = mfma16(a0, bb, acc[0][f]);
            acc[1][f] = mfma16(a1, bb, acc[1][f]);
        }
    }
#pragma unroll
    for (int mf = 0; mf < 2; ++mf)
#pragma unroll
        for (int f = 0; f < 4; ++f)
#pragma unroll
            for (int r = 0; r < 4; ++r) {
                int row = m0 + (mf << 4) + (lh << 2) + r;
                int col = (panel << 8) + (w << 6) + (f << 4) + lr;
                Out[(size_t)row * 1024 + col] = acc[mf][f][r];
            }
}

// ---------------------------------------------------------------------------
// Fused relation-net tile kernel. M=64 rows, 16 waves (1024 thr), 128KB LDS.
// Wave owns 64 output cols (acc[4][4]). 4 waves/SIMD for latency hiding.
// phase1: X=relu(A[i]+B[j]) -> GEMM1(W2,relu) -> packed Y (k'-perm) ->
// GEMM2(W3 pre-permuted) -> masked row-sum -> atomicAdd gsum.
// ---------------------------------------------------------------------------
struct FuseP {
    const float*  Arow;   // hq+bias folded
    const float*  Brow;
    const short8* W2;
    const short8* W3;
    const float*  b2;
    const float*  b3;
    float*        gsum;
    const int*    index;
    int           mode;   // 0: pairs=n*n (B 128 rows), 1: pairs=n*16 (B 16 rows)
};

__global__ __launch_bounds__(1024) void k_fused(FuseP P) {
    __shared__ short8 XL[8192];                       // 128 KiB
    int b  = blockIdx.y;
    int nv = P.index[b];
    int npairs = P.mode ? (nv << 4) : (nv * nv);
    int p0 = blockIdx.x << 6;
    if (p0 >= npairs) return;
    int tid = threadIdx.x, w = tid >> 6, l = tid & 63, lr = l & 15, lh = l >> 4;
    const float* Arow = P.Arow + (size_t)b * 128 * 1024;
    const float* Brow = P.Brow + (size_t)b * (P.mode ? 16 : 128) * 1024;

    // ---- phase 1: X tile. wave w -> (mfp = w>>2, t in (w&3)*8..+7)
    {
        int mfp = w >> 2;
        int p = p0 + (mfp << 4) + lr;
        int i = 0, j = 0;
        if (p < npairs) {
            if (P.mode) { i = p >> 4; j = p & 15; }
            else        { i = (int)((unsigned)p / (unsigned)nv); j = p - i * nv; }
        }
        const float* Ap = Arow + (size_t)i * 1024;
        const float* Bp = Brow + (size_t)j * 1024;
        int tbase = (w & 3) << 3;
#pragma unroll
        for (int cc = 0; cc < 8; ++cc) {
            int t = tbase + cc;
            int k0 = (t << 5) + (lh << 3);
            f32x4 a0 = *(const f32x4*)(Ap + k0), a1 = *(const f32x4*)(Ap + k0 + 4);
            f32x4 b0 = *(const f32x4*)(Bp + k0), b1 = *(const f32x4*)(Bp + k0 + 4);
            short8 v;
#pragma unroll
            for (int e = 0; e < 4; ++e) {
                v[e]     = f2bf(fmaxf(a0[e] + b0[e], 0.f));
                v[4 + e] = f2bf(fmaxf(a1[e] + b1[e], 0.f));
            }
            XL[swz((((mfp << 5) + t) << 6) + l)] = v;
        }
    }
    float b2l[4], b3l[4];
#pragma unroll
    for (int f = 0; f < 4; ++f) {
        int n = (w << 6) + (f << 4) + lr;
        b2l[f] = P.b2[n];
        b3l[f] = P.b3[n];
    }
    __syncthreads();

    // ---- GEMM1: Y = X @ W2  (wave cols w*64..+63)
    const short8* W2l = P.W2 + ((size_t)w << 13) + l;
    f32x4 z4 = {0.f, 0.f, 0.f, 0.f};
    f32x4 acc[4][4];
#pragma unroll
    for (int mf = 0; mf < 4; ++mf)
#pragma unroll
        for (int f = 0; f < 4; ++f) acc[mf][f] = z4;
    for (int t = 0; t < 32; ++t) {
        bf16x8 a[4];
#pragma unroll
        for (int mf = 0; mf < 4; ++mf)
            a[mf] = __builtin_bit_cast(bf16x8, XL[swz((((mf << 5) + t) << 6) + l)]);
#pragma unroll
        for (int f = 0; f < 4; ++f) {
            bf16x8 bb = __builtin_bit_cast(bf16x8, W2l[((f << 5) + t) << 6]);
#pragma unroll
            for (int mf = 0; mf < 4; ++mf)
                acc[mf][f] = mfma16(a[mf], bb, acc[mf][f]);
        }
    }
    __syncthreads();                                   // all X reads done

    // ---- epilogue 1: Y[m][k'] = relu(acc+b2), k' = w*64 + (lr>>3)*32 +
    // ((lr>>1)&3)*8 + (lr&1)*4 + f.  One b64 write per (mf,r).
    {
        unsigned long long* Y8 = (unsigned long long*)XL;
        int t2  = (w << 1) + (lr >> 3);
        int lh2 = (lr >> 1) & 3;
        int half = lr & 1;
#pragma unroll
        for (int mf = 0; mf < 4; ++mf)
#pragma unroll
            for (int r = 0; r < 4; ++r) {
                unsigned long long pk = 0;
#pragma unroll
                for (int f = 0; f < 4; ++f) {
                    unsigned short h = (unsigned short)f2bf(fmaxf(acc[mf][f][r] + b2l[f], 0.f));
                    pk |= (unsigned long long)h << (16 * f);
                }
                int lr2 = (lh << 2) + r;
                int slot = (((mf << 5) + t2) << 6) + (lh2 << 4) + lr2;
                Y8[(swz(slot) << 1) + half] = pk;
            }
    }
    __syncthreads();

    // ---- GEMM2: Z = Y @ W3 (k'-space; W3 rows pre-permuted)
    const short8* W3l = P.W3 + ((size_t)w << 13) + l;
#pragma unroll
    for (int mf = 0; mf < 4; ++mf)
#pragma unroll
        for (int f = 0; f < 4; ++f) acc[mf][f] = z4;
    for (int t = 0; t < 32; ++t) {
        bf16x8 a[4];
#pragma unroll
        for (int mf = 0; mf < 4; ++mf)
            a[mf] = __builtin_bit_cast(bf16x8, XL[swz((((mf << 5) + t) << 6) + l)]);
#pragma unroll
        for (int f = 0; f < 4; ++f) {
            bf16x8 bb = __builtin_bit_cast(bf16x8, W3l[((f << 5) + t) << 6]);
#pragma unroll
            for (int mf = 0; mf < 4; ++mf)
                acc[mf][f] = mfma16(a[mf], bb, acc[mf][f]);
        }
    }

    // ---- masked row-sum of relu(acc+b3) -> one atomic per col
#pragma unroll
    for (int f = 0; f < 4; ++f) {
        float s = 0.f;
#pragma unroll
        for (int mf = 0; mf < 4; ++mf)
#pragma unroll
            for (int r = 0; r < 4; ++r) {
                int m = (mf << 4) + (lh << 2) + r;
                if (p0 + m < npairs) s += fmaxf(acc[mf][f][r] + b3l[f], 0.f);
            }
        s += __shfl_xor(s, 16);
        s += __shfl_xor(s, 32);
        if (l < 16) atomicAdd(&P.gsum[(size_t)b * 1024 + (w << 6) + (f << 4) + l], s);
    }
}

// ---------------------------------------------------------------------------
// Tail (fp32, tiny)
// ---------------------------------------------------------------------------
__global__ __launch_bounds__(256) void k_t1(const float* g1s, const float* g2s,
                                            const float* f1_w, const float* f1_b,
                                            const float* f2_w, const float* f2_b,
                                            float* rn) {
    __shared__ float red[256];
    int bi = blockIdx.x;
    int s = bi >> 6, b = (bi >> 4) & 3, nb = bi & 15;
    int t = threadIdx.x, nl = t & 63, sl = t >> 6;
    int n = (nb << 6) + nl;
    const float* vin = (s ? g2s : g1s) + b * 1024;
    const float* W = s ? f2_w : f1_w;
    float p = 0.f;
    int k0 = sl << 8;
    for (int k = 0; k < 256; ++k) p += vin[k0 + k] * W[(size_t)(k0 + k) * 1024 + n];
    red[t] = p;
    __syncthreads();
    if (t < 64) {
        float tot = red[t] + red[t + 64] + red[t + 128] + red[t + 192];
        const float* bias = s ? f2_b : f1_b;
        int nn = (nb << 6) + t;
        rn[(size_t)b * 2048 + (s << 10) + nn] = fmaxf(tot + bias[nn], 0.f);
    }
}

__global__ __launch_bounds__(256) void k_t2(const float* rn, const float* fg_w1,
                                            const float* fg_b1, float* u) {
    __shared__ float red[256];
    int bi = blockIdx.x;
    int b = bi >> 4, nb = bi & 15;
    int t = threadIdx.x, nl = t & 63, sl = t >> 6;
    int n = (nb << 6) + nl;
    float p = 0.f;
    int k0 = sl << 9;
    for (int k = 0; k < 512; ++k) p += rn[(size_t)b * 2048 + k0 + k] * fg_w1[(size_t)(k0 + k) * 1024 + n];
    red[t] = p;
    __syncthreads();
    if (t < 64) {
        float tot = red[t] + red[t + 64] + red[t + 128] + red[t + 192];
        int nn = (nb << 6) + t;
        u[(size_t)b * 1024 + nn] = fmaxf(tot + fg_b1[nn], 0.f);
    }
}

__global__ __launch_bounds__(256) void k_t3(const float* u, const float* fg_w2,
                                            const float* fg_b2, float* out) {
    __shared__ float red[256];
    int b = blockIdx.x;
    int t = threadIdx.x, c = t & 15, sl = t >> 4;
    float p = 0.f;
    int k0 = sl << 6;
    for (int k = 0; k < 64; ++k) p += u[(size_t)b * 1024 + k0 + k] * fg_w2[(size_t)(k0 + k) * 16 + c];
    red[t] = p;
    __syncthreads();
    if (t < 16) {
        float tot = 0.f;
#pragma unroll
        for (int s2 = 0; s2 < 16; ++s2) tot += red[t + (s2 << 4)];
        out[b * 16 + t] = tot + fg_b2[t];
    }
}

// ---------------------------------------------------------------------------
extern "C" void kernel_launch(void* const* d_in, const int* in_sizes, int n_in,
                              void* d_out, int out_size, void* d_ws, size_t ws_size,
                              hipStream_t stream) {
    (void)in_sizes; (void)n_in; (void)out_size; (void)ws_size;
    const float* pooled      = (const float*)d_in[1];
    const float* box_feats   = (const float*)d_in[2];
    const float* q_feats     = (const float*)d_in[3];
    const float* box_coords  = (const float*)d_in[4];
    const int*   index       = (const int*)d_in[5];
    const float* g1_w1 = (const float*)d_in[6];
    const float* g1_b1 = (const float*)d_in[7];
    const float* g1_w2 = (const float*)d_in[8];
    const float* g1_b2 = (const float*)d_in[9];
    const float* g1_w3 = (const float*)d_in[10];
    const float* g1_b3 = (const float*)d_in[11];
    const float* f1_w  = (const float*)d_in[12];
    const float* f1_b  = (const float*)d_in[13];
    const float* g2_w1 = (const float*)d_in[14];
    const float* g2_b1 = (const float*)d_in[15];
    const float* g2_w2 = (const float*)d_in[16];
    const float* g2_b2 = (const float*)d_in[17];
    const float* g2_w3 = (const float*)d_in[18];
    const float* g2_b3 = (const float*)d_in[19];
    const float* f2_w  = (const float*)d_in[20];
    const float* f2_b  = (const float*)d_in[21];
    const float* fg_w1 = (const float*)d_in[22];
    const float* fg_b1 = (const float*)d_in[23];
    const float* fg_w2 = (const float*)d_in[24];
    const float* fg_b2 = (const float*)d_in[25];
    const float* pool_coords = (const float*)d_in[26];
    float* out = (float*)d_out;

    char* base = (char*)d_ws;
    size_t off = 0;
    auto alloc = [&](size_t bytes) -> void* {
        void* p = base + off;
        off = (off + bytes + 255) & ~(size_t)255;
        return p;
    };
    const size_t szWf98 = (size_t)98 * 64 * 64 * 16;  // 6.4 MB
    const size_t szWf65 = (size_t)65 * 64 * 64 * 16;  // 4.26 MB
    const size_t szWf32 = (size_t)32 * 64 * 64 * 16;  // 2 MB
    short* WfA   = (short*)alloc(szWf98);
    short* WfB   = (short*)alloc(szWf65);
    short* Wf2A  = (short*)alloc(szWf98);
    short* Wf2B  = (short*)alloc(szWf65);
    short* Wg1w2 = (short*)alloc(szWf32);
    short* Wg1w3 = (short*)alloc(szWf32);
    short* Wg2w2 = (short*)alloc(szWf32);
    short* Wg2w3 = (short*)alloc(szWf32);
    short* bfcq  = (short*)alloc((size_t)512 * 3136 * 2);
    short* pc    = (short*)alloc((size_t)64 * 2080 * 2);
    float* A1    = (float*)alloc((size_t)512 * 1024 * 4);
    float* B1    = (float*)alloc((size_t)512 * 1024 * 4);
    float* A2    = (float*)alloc((size_t)512 * 1024 * 4);
    float* P2    = (float*)alloc((size_t)64 * 1024 * 4);
    float* sums  = (float*)alloc((size_t)2 * 4096 * 4);
    float* g1s   = sums;
    float* g2s   = sums + 4096;
    float* rn    = (float*)alloc((size_t)4 * 2048 * 4);
    float* u     = (float*)alloc((size_t)4 * 1024 * 4);

    // 0. zero accumulators early (independent of other work)
    hipMemsetAsync(sums, 0, 2 * 4096 * 4, stream);

    // 1. repack weights
    WConvP wp;
    for (int y = 0; y < 8; ++y) { wp.srcq[y] = nullptr; wp.bias[y] = nullptr; wp.perm[y] = 0; }
    wp.src0[0] = g1_w1;                      wp.srcq[0] = g1_w1 + (size_t)4104*1024; wp.bias[0] = g1_b1;
    wp.dst[0] = WfA;   wp.n0[0] = 2052; wp.nK[0] = 98;
    wp.src0[1] = g1_w1 + (size_t)2052*1024;  wp.dst[1] = WfB;   wp.n0[1] = 2052; wp.nK[1] = 65;
    wp.src0[2] = g2_w1;                      wp.srcq[2] = g2_w1 + (size_t)4104*1024; wp.bias[2] = g2_b1;
    wp.dst[2] = Wf2A;  wp.n0[2] = 2052; wp.nK[2] = 98;
    wp.src0[3] = g2_w1 + (size_t)2052*1024;  wp.dst[3] = Wf2B;  wp.n0[3] = 2052; wp.nK[3] = 65;
    wp.src0[4] = g1_w2; wp.dst[4] = Wg1w2; wp.n0[4] = 1024; wp.nK[4] = 32;
    wp.src0[5] = g1_w3; wp.dst[5] = Wg1w3; wp.n0[5] = 1024; wp.nK[5] = 32; wp.perm[5] = 1;
    wp.src0[6] = g2_w2; wp.dst[6] = Wg2w2; wp.n0[6] = 1024; wp.nK[6] = 32;
    wp.src0[7] = g2_w3; wp.dst[7] = Wg2w3; wp.n0[7] = 1024; wp.nK[7] = 32; wp.perm[7] = 1;
    k_wconv<<<dim3(1568, 8), 256, 0, stream>>>(wp);

    // 2. padded bf16 activations (q + bias-row appended for A-paths)
    k_build<<<dim3(6272, 2), 256, 0, stream>>>(box_feats, box_coords, pooled, pool_coords,
                                               q_feats, bfcq, pc);

    // 3. stage-1 GEMMs: A1 (hq1+b1 folded), B1, A2 (hq2+b1 folded), P2
    S1P sp;
    sp.X[0] = bfcq; sp.Wf[0] = (const short8*)WfA;  sp.Out[0] = A1; sp.xstr[0] = 3136; sp.nK[0] = 98;
    sp.X[1] = bfcq; sp.Wf[1] = (const short8*)WfB;  sp.Out[1] = B1; sp.xstr[1] = 3136; sp.nK[1] = 65;
    sp.X[2] = bfcq; sp.Wf[2] = (const short8*)Wf2A; sp.Out[2] = A2; sp.xstr[2] = 3136; sp.nK[2] = 98;
    sp.X[3] = pc;   sp.Wf[3] = (const short8*)Wf2B; sp.Out[3] = P2; sp.xstr[3] = 2080; sp.nK[3] = 65;
    k_stage1<<<200, 256, 0, stream>>>(sp);

    // 4. fused g1 path (pairs = n*n), M=64, 16 waves
    FuseP f1p;
    f1p.Arow = A1; f1p.Brow = B1;
    f1p.W2 = (const short8*)Wg1w2; f1p.W3 = (const short8*)Wg1w3;
    f1p.b2 = g1_b2; f1p.b3 = g1_b3; f1p.gsum = g1s; f1p.index = index; f1p.mode = 0;
    k_fused<<<dim3(256, 4), 1024, 0, stream>>>(f1p);

    // 5. fused g2 path (pairs = n*16)
    FuseP f2p;
    f2p.Arow = A2; f2p.Brow = P2;
    f2p.W2 = (const short8*)Wg2w2; f2p.W3 = (const short8*)Wg2w3;
    f2p.b2 = g2_b2; f2p.b3 = g2_b3; f2p.gsum = g2s; f2p.index = index; f2p.mode = 1;
    k_fused<<<dim3(32, 4), 1024, 0, stream>>>(f2p);

    // 6-8. tail
    k_t1<<<128, 256, 0, stream>>>(g1s, g2s, f1_w, f1_b, f2_w, f2_b, rn);
    k_t2<<<64, 256, 0, stream>>>(rn, fg_w1, fg_b1, u);
    k_t3<<<4, 256, 0, stream>>>(u, fg_w2, fg_b2, out);
}